// Round 9
// baseline (255.067 us; speedup 1.0000x reference)
//
#include <hip/hip_runtime.h>
#include <hip/hip_bf16.h>

typedef __attribute__((ext_vector_type(8))) short short8;
typedef __attribute__((ext_vector_type(4))) float f32x4;

#define CHUNK 4

__device__ inline short f2bf(float f) {
    unsigned u = __builtin_bit_cast(unsigned, f);
    u += 0x7fffu + ((u >> 16) & 1u);
    return (short)(u >> 16);
}
__device__ inline float bf2f(short s) {
    return __builtin_bit_cast(float, ((unsigned)(unsigned short)s) << 16);
}
__device__ inline float bflo(unsigned u) { return __builtin_bit_cast(float, u << 16); }
__device__ inline float bfhi(unsigned u) { return __builtin_bit_cast(float, u & 0xffff0000u); }
__device__ inline unsigned cvt_pk_bf16(float a, float b) {
    unsigned r;
    asm("v_cvt_pk_bf16_f32 %0, %1, %2" : "=v"(r) : "v"(a), "v"(b));
    return r;
}
// tanh-form gelu: max abs err ~3e-3 vs exact
__device__ inline float gelu_fast(float x) {
    float z = x * (1.0f + 0.044715f * x * x);
    float e = __expf(1.5957691216f * z);
    return x - x * __builtin_amdgcn_rcpf(e + 1.0f);
}
__device__ inline float wred(float s) {
#pragma unroll
    for (int o = 32; o; o >>= 1) s += __shfl_xor(s, o, 64);
    return s;
}

// ---- pack all weights into bf16 MFMA-B fragment order -----------------------
__global__ void pack_all_kernel(const float* __restrict__ W1, const float* __restrict__ W2,
                                const float* __restrict__ W3, const float* __restrict__ W11,
                                const float* __restrict__ W12, const float* __restrict__ W13,
                                const float* __restrict__ Win, const float* __restrict__ Wout,
                                short* __restrict__ out) {
    int b = blockIdx.x;
    if (b < 80) {
        int which = b >> 3;
        const float* Ws[10] = {W1 + 128 * 128, W2, W3, W11 + 128 * 128, W12, W13,
                               W1, W1 + 256 * 128, W11, W11 + 256 * 128};
        const float* W = Ws[which];
        int i = (b & 7) * 256 + threadIdx.x;
        int lane = i & 63, tile = i >> 6;
        int kt = tile & 3, nt = tile >> 2;
        int n = nt * 16 + (lane & 15);
        int k0 = kt * 32 + (lane >> 4) * 8;
        short8 v;
#pragma unroll
        for (int j = 0; j < 8; ++j) v[j] = f2bf(W[(size_t)(k0 + j) * 128 + n]);
        *(short8*)(out + (size_t)which * 16384 + (size_t)i * 8) = v;
    } else if (b < 112) {
        int i = (b - 80) * 256 + threadIdx.x;
        int lane = i & 63, tile = i >> 6;
        int kt = tile & 3, nt = tile >> 2;
        int n = nt * 16 + (lane & 15);
        int k0 = kt * 32 + (lane >> 4) * 8;
        short8 v;
#pragma unroll
        for (int j = 0; j < 8; ++j) v[j] = f2bf(Win[(size_t)(k0 + j) * 512 + n]);
        *(short8*)(out + 163840 + (size_t)i * 8) = v;
    } else {
        int i = (b - 112) * 256 + threadIdx.x;
        int lane = i & 63, tile = i >> 6;
        int kt = tile & 15, nt = tile >> 4;
        int n = nt * 16 + (lane & 15);
        int k0 = kt * 32 + (lane >> 4) * 8;
        short8 v;
#pragma unroll
        for (int j = 0; j < 8; ++j) v[j] = f2bf(Wout[(size_t)(k0 + j) * 128 + n]);
        *(short8*)(out + 229376 + (size_t)i * 8) = v;
    }
}

// ---- node precompute via MFMA: Ys = x@Wself+b (f32), Yn = x@Wnbr (bf16) -----
__global__ __launch_bounds__(256) void node_pre_kernel(
    const float* __restrict__ hV, const short8* __restrict__ Bs,
    const short8* __restrict__ Bn, const float* __restrict__ bias,
    float* __restrict__ Ys, short* __restrict__ Yn) {
    int n0 = blockIdx.x * 16;
    int tid = threadIdx.x, lane = tid & 63, w = tid >> 6;
    __shared__ __align__(16) short A_sw[16 * 128];
    {
        int off = tid * 8;
        int r = off >> 7, c0 = off & 127;
        const float* src = hV + (size_t)n0 * 128 + off;
        float4 f0 = *(const float4*)(src);
        float4 f1 = *(const float4*)(src + 4);
        uint4 u;
        u.x = cvt_pk_bf16(f0.x, f0.y); u.y = cvt_pk_bf16(f0.z, f0.w);
        u.z = cvt_pk_bf16(f1.x, f1.y); u.w = cvt_pk_bf16(f1.z, f1.w);
        *(uint4*)((char*)A_sw + r * 256 + ((c0 * 2) ^ ((r & 7) << 4))) = u;
    }
    __syncthreads();
    const short8* Bp = (w < 2) ? Bs : Bn;
    f32x4 acc[4];
#pragma unroll
    for (int n2 = 0; n2 < 4; ++n2) acc[n2] = (f32x4){0.f, 0.f, 0.f, 0.f};
#pragma unroll
    for (int kt = 0; kt < 4; ++kt) {
        int row = lane & 15;
        int kb = (kt * 32 + (lane >> 4) * 8) * 2;
        short8 a = *(const short8*)((const char*)A_sw + row * 256 + (kb ^ ((row & 7) << 4)));
#pragma unroll
        for (int n2 = 0; n2 < 4; ++n2) {
            int ntl = (w & 1) * 4 + n2;
            short8 bf = Bp[(ntl * 4 + kt) * 64 + lane];
            acc[n2] = __builtin_amdgcn_mfma_f32_16x16x32_bf16(a, bf, acc[n2], 0, 0, 0);
        }
    }
    if (w < 2) {
#pragma unroll
        for (int n2 = 0; n2 < 4; ++n2) {
            int col = ((w & 1) * 4 + n2) * 16 + (lane & 15);
            float bv = bias[col];
#pragma unroll
            for (int i = 0; i < 4; ++i) {
                int row = (lane >> 4) * 4 + i;
                Ys[(size_t)(n0 + row) * 128 + col] = acc[n2][i] + bv;
            }
        }
    } else {
#pragma unroll
        for (int n2 = 0; n2 < 4; ++n2) {
            int col = ((w & 1) * 4 + n2) * 16 + (lane & 15);
#pragma unroll
            for (int i = 0; i < 4; ++i) {
                int row = (lane >> 4) * 4 + i;
                Yn[(size_t)(n0 + row) * 128 + col] = f2bf(acc[n2][i]);
            }
        }
    }
}

// ---- GEMM helpers on a 48x128 bf16 edge tile in swizzled LDS ---------------
// Tile byte(edge,feat) = edge*256 + ((feat*2) ^ ((edge&7)<<4))

__device__ inline void gemm48_a(const short* A_sw, const short8* __restrict__ Wp,
                                int w, int lane, f32x4 acc[3][2]) {
#pragma unroll
    for (int mt = 0; mt < 3; ++mt)
#pragma unroll
        for (int n2 = 0; n2 < 2; ++n2) acc[mt][n2] = (f32x4){0.f, 0.f, 0.f, 0.f};
#pragma unroll
    for (int kt = 0; kt < 4; ++kt) {
        short8 a[3];
        int kb = (kt * 32 + (lane >> 4) * 8) * 2;
#pragma unroll
        for (int mt = 0; mt < 3; ++mt) {
            int row = mt * 16 + (lane & 15);
            a[mt] = *(const short8*)((const char*)A_sw + row * 256 + (kb ^ ((row & 7) << 4)));
        }
#pragma unroll
        for (int n2 = 0; n2 < 2; ++n2) {
            short8 bf = Wp[((w * 2 + n2) * 4 + kt) * 64 + lane];
#pragma unroll
            for (int mt = 0; mt < 3; ++mt)
                acc[mt][n2] = __builtin_amdgcn_mfma_f32_16x16x32_bf16(a[mt], bf, acc[mt][n2], 0, 0, 0);
        }
    }
}

__device__ inline void gemm48_swz(const short* A_sw, const short8* __restrict__ Wp,
                                  int w, int lane, f32x4 acc[2][3]) {
#pragma unroll
    for (int m2 = 0; m2 < 2; ++m2)
#pragma unroll
        for (int nt = 0; nt < 3; ++nt) acc[m2][nt] = (f32x4){0.f, 0.f, 0.f, 0.f};
#pragma unroll
    for (int kt = 0; kt < 4; ++kt) {
        int kb = (kt * 32 + (lane >> 4) * 8) * 2;
        short8 e[3];
#pragma unroll
        for (int nt = 0; nt < 3; ++nt) {
            int row = nt * 16 + (lane & 15);
            e[nt] = *(const short8*)((const char*)A_sw + row * 256 + (kb ^ ((row & 7) << 4)));
        }
#pragma unroll
        for (int m2 = 0; m2 < 2; ++m2) {
            short8 wf = Wp[((w * 2 + m2) * 4 + kt) * 64 + lane];
#pragma unroll
            for (int nt = 0; nt < 3; ++nt)
                acc[m2][nt] = __builtin_amdgcn_mfma_f32_16x16x32_bf16(wf, e[nt], acc[m2][nt], 0, 0, 0);
        }
    }
}

// split staging: issue loads early, convert+write late (T14)
__device__ inline void stage_load(const float* __restrict__ Eb, int tid, float4 f[6]) {
#pragma unroll
    for (int i = 0; i < 3; ++i) {
        int e = tid + i * 256;
        int r = e >> 4, c0 = (e & 15) * 8;
        f[2 * i] = *(const float4*)(Eb + r * 128 + c0);
        f[2 * i + 1] = *(const float4*)(Eb + r * 128 + c0 + 4);
    }
}
__device__ inline void stage_write(const float4 f[6], short* A_sw, int tid) {
#pragma unroll
    for (int i = 0; i < 3; ++i) {
        int e = tid + i * 256;
        int r = e >> 4, c0 = (e & 15) * 8;
        uint4 u;
        u.x = cvt_pk_bf16(f[2 * i].x, f[2 * i].y);
        u.y = cvt_pk_bf16(f[2 * i].z, f[2 * i].w);
        u.z = cvt_pk_bf16(f[2 * i + 1].x, f[2 * i + 1].y);
        u.w = cvt_pk_bf16(f[2 * i + 1].z, f[2 * i + 1].w);
        *(uint4*)((char*)A_sw + r * 256 + ((c0 * 2) ^ ((r & 7) << 4))) = u;
    }
}

// per-lane prefetch of Yn[E_idx] fragments + Ys fragments into registers
__device__ inline void prefetch_yn_ys(const short* __restrict__ Yng,
                                      const float* __restrict__ Ysg,
                                      const int* __restrict__ Eidx,
                                      int node, int bb, int e0, int featb0, int featb1,
                                      uint2 ynv[3][2], float4 ysv[2]) {
    int i0 = Eidx[node * 48 + e0];
    int i1 = Eidx[node * 48 + 16 + e0];
    int i2 = Eidx[node * 48 + 32 + e0];
    const short* Y0 = Yng + ((size_t)bb * 2048 + i0) * 128;
    const short* Y1 = Yng + ((size_t)bb * 2048 + i1) * 128;
    const short* Y2 = Yng + ((size_t)bb * 2048 + i2) * 128;
    ynv[0][0] = *(const uint2*)(Y0 + featb0); ynv[0][1] = *(const uint2*)(Y0 + featb1);
    ynv[1][0] = *(const uint2*)(Y1 + featb0); ynv[1][1] = *(const uint2*)(Y1 + featb1);
    ynv[2][0] = *(const uint2*)(Y2 + featb0); ynv[2][1] = *(const uint2*)(Y2 + featb1);
    ysv[0] = *(const float4*)(Ysg + (size_t)node * 128 + featb0);
    ysv[1] = *(const float4*)(Ysg + (size_t)node * 128 + featb1);
}

// layer-1 epilogue (swapped): v = gelu(acc + Ys[feat] + Yn[edge][feat]) -> tile
__device__ inline void epi_l1_reg(f32x4 acc[2][3], const float4 ysv[2],
                                  const uint2 ynv[3][2], short* A_sw, int w, int lane) {
#pragma unroll
    for (int m2 = 0; m2 < 2; ++m2) {
        int featb = (w * 2 + m2) * 16 + ((lane >> 4) << 2);
#pragma unroll
        for (int nt = 0; nt < 3; ++nt) {
            int edge = nt * 16 + (lane & 15);
            uint2 yv = ynv[nt][m2];
            float v0 = gelu_fast(acc[m2][nt][0] + ysv[m2].x + bflo(yv.x));
            float v1 = gelu_fast(acc[m2][nt][1] + ysv[m2].y + bfhi(yv.x));
            float v2 = gelu_fast(acc[m2][nt][2] + ysv[m2].z + bflo(yv.y));
            float v3 = gelu_fast(acc[m2][nt][3] + ysv[m2].w + bfhi(yv.y));
            uint2 pk = {cvt_pk_bf16(v0, v1), cvt_pk_bf16(v2, v3)};
            *(uint2*)((char*)A_sw + edge * 256 + ((featb * 2) ^ ((edge & 7) << 4))) = pk;
        }
    }
}

// layer-2 epilogue (swapped): v = gelu(acc + b[feat]) -> tile
__device__ inline void epi_l2(f32x4 acc[2][3], const float* __restrict__ b,
                              short* A_sw, int w, int lane) {
#pragma unroll
    for (int m2 = 0; m2 < 2; ++m2) {
        int featb = (w * 2 + m2) * 16 + ((lane >> 4) << 2);
        float b0 = b[featb], b1 = b[featb + 1], b2v = b[featb + 2], b3v = b[featb + 3];
#pragma unroll
        for (int nt = 0; nt < 3; ++nt) {
            int edge = nt * 16 + (lane & 15);
            float v0 = gelu_fast(acc[m2][nt][0] + b0);
            float v1 = gelu_fast(acc[m2][nt][1] + b1);
            float v2 = gelu_fast(acc[m2][nt][2] + b2v);
            float v3 = gelu_fast(acc[m2][nt][3] + b3v);
            uint2 pk = {cvt_pk_bf16(v0, v1), cvt_pk_bf16(v2, v3)};
            *(uint2*)((char*)A_sw + edge * 256 + ((featb * 2) ^ ((edge & 7) << 4))) = pk;
        }
    }
}

// ---- node message MLP + masked mean + LN1 (pipelined over CHUNK nodes) ------
__global__ __launch_bounds__(256) void node_msg_kernel(
    const float* __restrict__ hV, const float* __restrict__ hE,
    const int* __restrict__ Eidx, const float* __restrict__ maskAtt,
    const short8* __restrict__ W1bp, const short8* __restrict__ W2p,
    const short8* __restrict__ W3p, const float* __restrict__ b2,
    const float* __restrict__ b3, const float* __restrict__ Ysg,
    const short* __restrict__ Yng, const float* __restrict__ g1,
    const float* __restrict__ be1, float* __restrict__ hv1out) {
    const int base = blockIdx.x * CHUNK;
    const int bb = base >> 11;        // CHUNK-aligned: whole chunk in same batch
    const int tid = threadIdx.x;
    const int lane = tid & 63, w = tid >> 6;

    __shared__ __align__(16) short A_sw[2][48 * 128];
    __shared__ float mask_s[2][48];
    __shared__ float red[8];

    const int e0 = lane & 15;
    const int featb0 = (w * 2) * 16 + ((lane >> 4) << 2);
    const int featb1 = featb0 + 16;

    uint2 ynv[3][2], ynv_n[3][2];
    float4 ysv[2], ysv_n[2];
    float4 fst[6];

    // prologue: stage node `base` into buf 0
    prefetch_yn_ys(Yng, Ysg, Eidx, base, bb, e0, featb0, featb1, ynv, ysv);
    stage_load(hE + (size_t)base * 6144, tid, fst);
    stage_write(fst, A_sw[0], tid);
    if (tid < 48) mask_s[0][tid] = maskAtt[base * 48 + tid];
    __syncthreads();

    for (int k = 0; k < CHUNK; ++k) {
        const int node = base + k;
        const int p = k & 1;
        const bool more = (k + 1 < CHUNK);

        if (more) stage_load(hE + (size_t)(node + 1) * 6144, tid, fst);  // issue early

        f32x4 acc[2][3];
        gemm48_swz(A_sw[p], W1bp, w, lane, acc);
        __syncthreads();
        epi_l1_reg(acc, ysv, ynv, A_sw[p], w, lane);
        if (more) {
            prefetch_yn_ys(Yng, Ysg, Eidx, node + 1, bb, e0, featb0, featb1, ynv_n, ysv_n);
            if (tid < 48) mask_s[p ^ 1][tid] = maskAtt[(node + 1) * 48 + tid];
        }
        __syncthreads();
        gemm48_swz(A_sw[p], W2p, w, lane, acc);
        __syncthreads();
        if (more) stage_write(fst, A_sw[p ^ 1], tid);   // buf p^1 free; write late
        epi_l2(acc, b2, A_sw[p], w, lane);
        __syncthreads();

        // layer 3 (old orientation) + masked column-sum from accumulators
        f32x4 acc3[3][2];
        gemm48_a(A_sw[p], W3p, w, lane, acc3);
        float u[2];
#pragma unroll
        for (int n2 = 0; n2 < 2; ++n2) {
            int col = (w * 2 + n2) * 16 + (lane & 15);
            float b3c = b3[col];
            float s = 0.f;
#pragma unroll
            for (int mt = 0; mt < 3; ++mt)
#pragma unroll
                for (int i = 0; i < 4; ++i) {
                    int row = mt * 16 + (lane >> 4) * 4 + i;
                    s += (acc3[mt][n2][i] + b3c) * mask_s[p][row];
                }
            s += __shfl_xor(s, 16, 64);
            s += __shfl_xor(s, 32, 64);
            u[n2] = hV[(size_t)node * 128 + col] + s * (1.0f / 30.0f);
        }
        float ps = wred(u[0] + u[1]) * 0.25f;
        float pq = wred(u[0] * u[0] + u[1] * u[1]) * 0.25f;
        if (lane == 0) { red[w] = ps; red[4 + w] = pq; }
        __syncthreads();
        float S = red[0] + red[1] + red[2] + red[3];
        float Q = red[4] + red[5] + red[6] + red[7];
        float mu = S * (1.0f / 128.0f);
        float var = Q * (1.0f / 128.0f) - mu * mu;
        float rs = rsqrtf(var + 1e-5f);
        if ((lane >> 4) == 0) {
#pragma unroll
            for (int n2 = 0; n2 < 2; ++n2) {
                int col = (w * 2 + n2) * 16 + (lane & 15);
                hv1out[(size_t)node * 128 + col] = (u[n2] - mu) * rs * g1[col] + be1[col];
            }
        }
        __syncthreads();   // red[] / buffers safe for next iteration

        if (more) {
#pragma unroll
            for (int nt = 0; nt < 3; ++nt) { ynv[nt][0] = ynv_n[nt][0]; ynv[nt][1] = ynv_n[nt][1]; }
            ysv[0] = ysv_n[0]; ysv[1] = ysv_n[1];
        }
    }
}

// ---- FFN via MFMA: [16x128]@[128x512] gelu @[512x128] + residual + LN2 ------
__global__ __launch_bounds__(256) void ffn_kernel(
    const float* __restrict__ hv1, const short8* __restrict__ Winp,
    const float* __restrict__ binp, const short8* __restrict__ Woutp,
    const float* __restrict__ bout, const float* __restrict__ g2,
    const float* __restrict__ be2, const float* __restrict__ maskV,
    float* __restrict__ hVout) {
    int n0 = blockIdx.x * 16;
    int tid = threadIdx.x, lane = tid & 63, w = tid >> 6;
    __shared__ float X[16 * 128];
    __shared__ __align__(16) short A_sw[16 * 128];
    __shared__ __align__(16) short H_sw[16 * 512];

    {
        int off = tid * 8;
        int r = off >> 7, c0 = off & 127;
        const float* src = hv1 + (size_t)n0 * 128 + off;
        float4 f0 = *(const float4*)(src);
        float4 f1 = *(const float4*)(src + 4);
        *(float4*)(&X[off]) = f0;
        *(float4*)(&X[off + 4]) = f1;
        uint4 u;
        u.x = cvt_pk_bf16(f0.x, f0.y); u.y = cvt_pk_bf16(f0.z, f0.w);
        u.z = cvt_pk_bf16(f1.x, f1.y); u.w = cvt_pk_bf16(f1.z, f1.w);
        *(uint4*)((char*)A_sw + r * 256 + ((c0 * 2) ^ ((r & 7) << 4))) = u;
    }
    __syncthreads();

    f32x4 acc1[8];
#pragma unroll
    for (int n2 = 0; n2 < 8; ++n2) acc1[n2] = (f32x4){0.f, 0.f, 0.f, 0.f};
#pragma unroll
    for (int kt = 0; kt < 4; ++kt) {
        int row = lane & 15;
        int kb = (kt * 32 + (lane >> 4) * 8) * 2;
        short8 a = *(const short8*)((const char*)A_sw + row * 256 + (kb ^ ((row & 7) << 4)));
#pragma unroll
        for (int n2 = 0; n2 < 8; ++n2) {
            short8 bf = Winp[((w * 8 + n2) * 4 + kt) * 64 + lane];
            acc1[n2] = __builtin_amdgcn_mfma_f32_16x16x32_bf16(a, bf, acc1[n2], 0, 0, 0);
        }
    }
#pragma unroll
    for (int n2 = 0; n2 < 8; ++n2) {
        int col = (w * 8 + n2) * 16 + (lane & 15);
        float bv = binp[col];
#pragma unroll
        for (int i = 0; i < 4; ++i) {
            int row = (lane >> 4) * 4 + i;
            float v = gelu_fast(acc1[n2][i] + bv);
            *(short*)((char*)H_sw + row * 1024 + ((col * 2) ^ ((row & 7) << 4))) = f2bf(v);
        }
    }
    __syncthreads();

    f32x4 acc2[2];
    acc2[0] = (f32x4){0.f, 0.f, 0.f, 0.f};
    acc2[1] = (f32x4){0.f, 0.f, 0.f, 0.f};
#pragma unroll
    for (int kt = 0; kt < 16; ++kt) {
        int row = lane & 15;
        int kb = (kt * 32 + (lane >> 4) * 8) * 2;
        short8 a = *(const short8*)((const char*)H_sw + row * 1024 + (kb ^ ((row & 7) << 4)));
#pragma unroll
        for (int n2 = 0; n2 < 2; ++n2) {
            short8 bf = Woutp[((w * 2 + n2) * 16 + kt) * 64 + lane];
            acc2[n2] = __builtin_amdgcn_mfma_f32_16x16x32_bf16(a, bf, acc2[n2], 0, 0, 0);
        }
    }
#pragma unroll
    for (int n2 = 0; n2 < 2; ++n2) {
        int col = (w * 2 + n2) * 16 + (lane & 15);
        float bo = bout[col];
#pragma unroll
        for (int i = 0; i < 4; ++i) {
            int row = (lane >> 4) * 4 + i;
            X[row * 128 + col] += acc2[n2][i] + bo;
        }
    }
    __syncthreads();

#pragma unroll
    for (int p = 0; p < 4; ++p) {
        int r = p * 4 + w;
        float u0 = X[r * 128 + lane], u1 = X[r * 128 + lane + 64];
        float s = wred(u0 + u1);
        float q = wred(u0 * u0 + u1 * u1);
        float mu = s * (1.0f / 128.0f);
        float var = q * (1.0f / 128.0f) - mu * mu;
        float rs = rsqrtf(var + 1e-5f);
        float mv = maskV[n0 + r];
        hVout[(size_t)(n0 + r) * 128 + lane] = mv * ((u0 - mu) * rs * g2[lane] + be2[lane]);
        hVout[(size_t)(n0 + r) * 128 + lane + 64] = mv * ((u1 - mu) * rs * g2[lane + 64] + be2[lane + 64]);
    }
}

// ---- edge update MLP + residual + LN3 (pipelined over CHUNK nodes) ----------
__global__ __launch_bounds__(256) void edge_upd_kernel(
    const float* __restrict__ hE, const int* __restrict__ Eidx,
    const short8* __restrict__ W11bp, const short8* __restrict__ W12p,
    const short8* __restrict__ W13p, const float* __restrict__ b12,
    const float* __restrict__ b13, const float* __restrict__ Ysg,
    const short* __restrict__ Yng, const float* __restrict__ g3,
    const float* __restrict__ be3, float* __restrict__ hEout) {
    const int base = blockIdx.x * CHUNK;
    const int bb = base >> 11;
    const int tid = threadIdx.x;
    const int lane = tid & 63, w = tid >> 6;

    __shared__ __align__(16) short A_sw[2][48 * 128];

    const int e0 = lane & 15;
    const int featb0 = (w * 2) * 16 + ((lane >> 4) << 2);
    const int featb1 = featb0 + 16;

    uint2 ynv[3][2], ynv_n[3][2];
    float4 ysv[2], ysv_n[2];
    float4 fst[6];

    prefetch_yn_ys(Yng, Ysg, Eidx, base, bb, e0, featb0, featb1, ynv, ysv);
    stage_load(hE + (size_t)base * 6144, tid, fst);
    stage_write(fst, A_sw[0], tid);
    __syncthreads();

    for (int k = 0; k < CHUNK; ++k) {
        const int node = base + k;
        const int p = k & 1;
        const bool more = (k + 1 < CHUNK);
        const float* Eb = hE + (size_t)node * 6144;

        if (more) stage_load(hE + (size_t)(node + 1) * 6144, tid, fst);  // issue early

        f32x4 acc[2][3];
        gemm48_swz(A_sw[p], W11bp, w, lane, acc);
        __syncthreads();
        epi_l1_reg(acc, ysv, ynv, A_sw[p], w, lane);
        if (more) prefetch_yn_ys(Yng, Ysg, Eidx, node + 1, bb, e0, featb0, featb1, ynv_n, ysv_n);
        __syncthreads();
        gemm48_swz(A_sw[p], W12p, w, lane, acc);
        __syncthreads();
        // residual + b13 prefetch for current node (lands under epi2+gemm3)
        float4 resv[3][2];
#pragma unroll
        for (int nt = 0; nt < 3; ++nt) {
            int edge = nt * 16 + e0;
            resv[nt][0] = *(const float4*)(Eb + edge * 128 + featb0);
            resv[nt][1] = *(const float4*)(Eb + edge * 128 + featb1);
        }
        float4 b13v0 = *(const float4*)(b13 + featb0);
        float4 b13v1 = *(const float4*)(b13 + featb1);
        if (more) stage_write(fst, A_sw[p ^ 1], tid);   // write next tile late
        epi_l2(acc, b12, A_sw[p], w, lane);
        __syncthreads();

        gemm48_swz(A_sw[p], W13p, w, lane, acc);
        __syncthreads();   // all reads of tile done before stash reuse

        // stash pre-LN = acc + b13 + residual into A_sw[p] (same swizzle)
#pragma unroll
        for (int m2 = 0; m2 < 2; ++m2) {
            float4 bv = m2 ? b13v1 : b13v0;
            int featb = m2 ? featb1 : featb0;
#pragma unroll
            for (int nt = 0; nt < 3; ++nt) {
                int edge = nt * 16 + e0;
                float v0 = acc[m2][nt][0] + bv.x + resv[nt][m2].x;
                float v1 = acc[m2][nt][1] + bv.y + resv[nt][m2].y;
                float v2 = acc[m2][nt][2] + bv.z + resv[nt][m2].z;
                float v3 = acc[m2][nt][3] + bv.w + resv[nt][m2].w;
                uint2 pk = {cvt_pk_bf16(v0, v1), cvt_pk_bf16(v2, v3)};
                *(uint2*)((char*)A_sw[p] + edge * 256 + ((featb * 2) ^ ((edge & 7) << 4))) = pk;
            }
        }
        __syncthreads();

        // LN per edge row (wave per row), reading bf16 stash from swizzled A_sw[p]
        float* outb = hEout + (size_t)node * 6144;
        float gl0 = g3[lane], gl1 = g3[lane + 64];
        float bl0 = be3[lane], bl1 = be3[lane + 64];
#pragma unroll
        for (int pr = 0; pr < 12; ++pr) {
            int r = pr * 4 + w;
            int sw = (r & 7) << 4;
            float u0 = bf2f(*(const short*)((const char*)A_sw[p] + r * 256 + ((2 * lane) ^ sw)));
            float u1 = bf2f(*(const short*)((const char*)A_sw[p] + r * 256 + ((2 * lane + 128) ^ sw)));
            float s = wred(u0 + u1);
            float q = wred(u0 * u0 + u1 * u1);
            float mu = s * (1.0f / 128.0f);
            float var = q * (1.0f / 128.0f) - mu * mu;
            float rs = rsqrtf(var + 1e-5f);
            outb[r * 128 + lane] = (u0 - mu) * rs * gl0 + bl0;
            outb[r * 128 + lane + 64] = (u1 - mu) * rs * gl1 + bl1;
        }
        __syncthreads();   // stash reads done before next iteration reuses buffers

        if (more) {
#pragma unroll
            for (int nt = 0; nt < 3; ++nt) { ynv[nt][0] = ynv_n[nt][0]; ynv[nt][1] = ynv_n[nt][1]; }
            ysv[0] = ysv_n[0]; ysv[1] = ysv_n[1];
        }
    }
}

extern "C" void kernel_launch(void* const* d_in, const int* in_sizes, int n_in,
                              void* d_out, int out_size, void* d_ws, size_t ws_size,
                              hipStream_t stream) {
    const float* hV      = (const float*)d_in[0];
    const float* hE      = (const float*)d_in[1];
    const int*   Eidx    = (const int*)d_in[2];
    const float* maskV   = (const float*)d_in[3];
    const float* maskAtt = (const float*)d_in[4];
    const float* W1  = (const float*)d_in[5];
    const float* b1  = (const float*)d_in[6];
    const float* W2  = (const float*)d_in[7];
    const float* b2  = (const float*)d_in[8];
    const float* W3  = (const float*)d_in[9];
    const float* b3  = (const float*)d_in[10];
    const float* W11 = (const float*)d_in[11];
    const float* b11 = (const float*)d_in[12];
    const float* W12 = (const float*)d_in[13];
    const float* b12 = (const float*)d_in[14];
    const float* W13 = (const float*)d_in[15];
    const float* b13 = (const float*)d_in[16];
    const float* Win = (const float*)d_in[17];
    const float* binp= (const float*)d_in[18];
    const float* Wout= (const float*)d_in[19];
    const float* bout= (const float*)d_in[20];
    const float* g1  = (const float*)d_in[21];
    const float* be1 = (const float*)d_in[22];
    const float* g2  = (const float*)d_in[23];
    const float* be2 = (const float*)d_in[24];
    const float* g3  = (const float*)d_in[25];
    const float* be3 = (const float*)d_in[26];

    char* ws = (char*)d_ws;
    short* Wpk  = (short*)ws;
    float* Ys   = (float*)(ws + 1048576);
    short* Yn   = (short*)(ws + 1048576 + 2097152);
    float* hv1  = (float*)(ws + 1048576 + 2097152 + 1048576);

    float* hVout = (float*)d_out;
    float* hEout = hVout + 2 * 2048 * 128;

    const int NNODE = 2 * 2048;

    pack_all_kernel<<<144, 256, 0, stream>>>(W1, W2, W3, W11, W12, W13, Win, Wout, Wpk);

    node_pre_kernel<<<NNODE / 16, 256, 0, stream>>>(hV,
        (const short8*)(Wpk + 98304), (const short8*)(Wpk + 114688), b1, Ys, Yn);

    node_msg_kernel<<<NNODE / CHUNK, 256, 0, stream>>>(hV, hE, Eidx, maskAtt,
        (const short8*)(Wpk), (const short8*)(Wpk + 16384), (const short8*)(Wpk + 32768),
        b2, b3, Ys, Yn, g1, be1, hv1);

    ffn_kernel<<<NNODE / 16, 256, 0, stream>>>(hv1,
        (const short8*)(Wpk + 163840), binp, (const short8*)(Wpk + 229376), bout,
        g2, be2, maskV, hVout);

    node_pre_kernel<<<NNODE / 16, 256, 0, stream>>>(hVout,
        (const short8*)(Wpk + 131072), (const short8*)(Wpk + 147456), b11, Ys, Yn);

    edge_upd_kernel<<<NNODE / CHUNK, 256, 0, stream>>>(hE, Eidx,
        (const short8*)(Wpk + 49152), (const short8*)(Wpk + 65536), (const short8*)(Wpk + 81920),
        b12, b13, Ys, Yn, g3, be3, hEout);
}

// Round 10
// 153.339 us; speedup vs baseline: 1.6634x; 1.6634x over previous
//
#include <hip/hip_runtime.h>
#include <hip/hip_bf16.h>

typedef __attribute__((ext_vector_type(8))) short short8;
typedef __attribute__((ext_vector_type(4))) float f32x4;

__device__ inline short f2bf(float f) {
    unsigned u = __builtin_bit_cast(unsigned, f);
    u += 0x7fffu + ((u >> 16) & 1u);
    return (short)(u >> 16);
}
__device__ inline float bf2f(short s) {
    return __builtin_bit_cast(float, ((unsigned)(unsigned short)s) << 16);
}
__device__ inline float bflo(unsigned u) { return __builtin_bit_cast(float, u << 16); }
__device__ inline float bfhi(unsigned u) { return __builtin_bit_cast(float, u & 0xffff0000u); }
__device__ inline unsigned cvt_pk_bf16(float a, float b) {
    unsigned r;
    asm("v_cvt_pk_bf16_f32 %0, %1, %2" : "=v"(r) : "v"(a), "v"(b));
    return r;
}
// tanh-form gelu: max abs err ~3e-3 vs exact
__device__ inline float gelu_fast(float x) {
    float z = x * (1.0f + 0.044715f * x * x);
    float e = __expf(1.5957691216f * z);
    return x - x * __builtin_amdgcn_rcpf(e + 1.0f);
}
__device__ inline float wred(float s) {
#pragma unroll
    for (int o = 32; o; o >>= 1) s += __shfl_xor(s, o, 64);
    return s;
}

// ---- pack all weights into bf16 MFMA-B fragment order -----------------------
__global__ void pack_all_kernel(const float* __restrict__ W1, const float* __restrict__ W2,
                                const float* __restrict__ W3, const float* __restrict__ W11,
                                const float* __restrict__ W12, const float* __restrict__ W13,
                                const float* __restrict__ Win, const float* __restrict__ Wout,
                                short* __restrict__ out) {
    int b = blockIdx.x;
    if (b < 80) {
        int which = b >> 3;
        const float* Ws[10] = {W1 + 128 * 128, W2, W3, W11 + 128 * 128, W12, W13,
                               W1, W1 + 256 * 128, W11, W11 + 256 * 128};
        const float* W = Ws[which];
        int i = (b & 7) * 256 + threadIdx.x;
        int lane = i & 63, tile = i >> 6;
        int kt = tile & 3, nt = tile >> 2;
        int n = nt * 16 + (lane & 15);
        int k0 = kt * 32 + (lane >> 4) * 8;
        short8 v;
#pragma unroll
        for (int j = 0; j < 8; ++j) v[j] = f2bf(W[(size_t)(k0 + j) * 128 + n]);
        *(short8*)(out + (size_t)which * 16384 + (size_t)i * 8) = v;
    } else if (b < 112) {
        int i = (b - 80) * 256 + threadIdx.x;
        int lane = i & 63, tile = i >> 6;
        int kt = tile & 3, nt = tile >> 2;
        int n = nt * 16 + (lane & 15);
        int k0 = kt * 32 + (lane >> 4) * 8;
        short8 v;
#pragma unroll
        for (int j = 0; j < 8; ++j) v[j] = f2bf(Win[(size_t)(k0 + j) * 512 + n]);
        *(short8*)(out + 163840 + (size_t)i * 8) = v;
    } else {
        int i = (b - 112) * 256 + threadIdx.x;
        int lane = i & 63, tile = i >> 6;
        int kt = tile & 15, nt = tile >> 4;
        int n = nt * 16 + (lane & 15);
        int k0 = kt * 32 + (lane >> 4) * 8;
        short8 v;
#pragma unroll
        for (int j = 0; j < 8; ++j) v[j] = f2bf(Wout[(size_t)(k0 + j) * 128 + n]);
        *(short8*)(out + 229376 + (size_t)i * 8) = v;
    }
}

// ---- node precompute via MFMA: Ys = x@Wself+b (f32), Yn = x@Wnbr (bf16) -----
__global__ __launch_bounds__(256) void node_pre_kernel(
    const float* __restrict__ hV, const short8* __restrict__ Bs,
    const short8* __restrict__ Bn, const float* __restrict__ bias,
    float* __restrict__ Ys, short* __restrict__ Yn) {
    int n0 = blockIdx.x * 16;
    int tid = threadIdx.x, lane = tid & 63, w = tid >> 6;
    __shared__ __align__(16) short A_sw[16 * 128];
    {
        int off = tid * 8;
        int r = off >> 7, c0 = off & 127;
        const float* src = hV + (size_t)n0 * 128 + off;
        float4 f0 = *(const float4*)(src);
        float4 f1 = *(const float4*)(src + 4);
        uint4 u;
        u.x = cvt_pk_bf16(f0.x, f0.y); u.y = cvt_pk_bf16(f0.z, f0.w);
        u.z = cvt_pk_bf16(f1.x, f1.y); u.w = cvt_pk_bf16(f1.z, f1.w);
        *(uint4*)((char*)A_sw + r * 256 + ((c0 * 2) ^ ((r & 7) << 4))) = u;
    }
    __syncthreads();
    const short8* Bp = (w < 2) ? Bs : Bn;
    f32x4 acc[4];
#pragma unroll
    for (int n2 = 0; n2 < 4; ++n2) acc[n2] = (f32x4){0.f, 0.f, 0.f, 0.f};
#pragma unroll
    for (int kt = 0; kt < 4; ++kt) {
        int row = lane & 15;
        int kb = (kt * 32 + (lane >> 4) * 8) * 2;
        short8 a = *(const short8*)((const char*)A_sw + row * 256 + (kb ^ ((row & 7) << 4)));
#pragma unroll
        for (int n2 = 0; n2 < 4; ++n2) {
            int ntl = (w & 1) * 4 + n2;
            short8 bf = Bp[(ntl * 4 + kt) * 64 + lane];
            acc[n2] = __builtin_amdgcn_mfma_f32_16x16x32_bf16(a, bf, acc[n2], 0, 0, 0);
        }
    }
    if (w < 2) {
#pragma unroll
        for (int n2 = 0; n2 < 4; ++n2) {
            int col = ((w & 1) * 4 + n2) * 16 + (lane & 15);
            float bv = bias[col];
#pragma unroll
            for (int i = 0; i < 4; ++i) {
                int row = (lane >> 4) * 4 + i;
                Ys[(size_t)(n0 + row) * 128 + col] = acc[n2][i] + bv;
            }
        }
    } else {
#pragma unroll
        for (int n2 = 0; n2 < 4; ++n2) {
            int col = ((w & 1) * 4 + n2) * 16 + (lane & 15);
#pragma unroll
            for (int i = 0; i < 4; ++i) {
                int row = (lane >> 4) * 4 + i;
                Yn[(size_t)(n0 + row) * 128 + col] = f2bf(acc[n2][i]);
            }
        }
    }
}

// ---- GEMM helpers on a 48x128 bf16 edge tile in swizzled LDS ---------------
// Tile byte(edge,feat) = edge*256 + ((feat*2) ^ ((edge&7)<<4))

__device__ inline void gemm48_a(const short* A_sw, const short8* __restrict__ Wp,
                                int w, int lane, f32x4 acc[3][2]) {
#pragma unroll
    for (int mt = 0; mt < 3; ++mt)
#pragma unroll
        for (int n2 = 0; n2 < 2; ++n2) acc[mt][n2] = (f32x4){0.f, 0.f, 0.f, 0.f};
#pragma unroll
    for (int kt = 0; kt < 4; ++kt) {
        short8 a[3];
        int kb = (kt * 32 + (lane >> 4) * 8) * 2;
#pragma unroll
        for (int mt = 0; mt < 3; ++mt) {
            int row = mt * 16 + (lane & 15);
            a[mt] = *(const short8*)((const char*)A_sw + row * 256 + (kb ^ ((row & 7) << 4)));
        }
#pragma unroll
        for (int n2 = 0; n2 < 2; ++n2) {
            short8 bf = Wp[((w * 2 + n2) * 4 + kt) * 64 + lane];
#pragma unroll
            for (int mt = 0; mt < 3; ++mt)
                acc[mt][n2] = __builtin_amdgcn_mfma_f32_16x16x32_bf16(a[mt], bf, acc[mt][n2], 0, 0, 0);
        }
    }
}

__device__ inline void gemm48_swz(const short* A_sw, const short8* __restrict__ Wp,
                                  int w, int lane, f32x4 acc[2][3]) {
#pragma unroll
    for (int m2 = 0; m2 < 2; ++m2)
#pragma unroll
        for (int nt = 0; nt < 3; ++nt) acc[m2][nt] = (f32x4){0.f, 0.f, 0.f, 0.f};
#pragma unroll
    for (int kt = 0; kt < 4; ++kt) {
        int kb = (kt * 32 + (lane >> 4) * 8) * 2;
        short8 e[3];
#pragma unroll
        for (int nt = 0; nt < 3; ++nt) {
            int row = nt * 16 + (lane & 15);
            e[nt] = *(const short8*)((const char*)A_sw + row * 256 + (kb ^ ((row & 7) << 4)));
        }
#pragma unroll
        for (int m2 = 0; m2 < 2; ++m2) {
            short8 wf = Wp[((w * 2 + m2) * 4 + kt) * 64 + lane];
#pragma unroll
            for (int nt = 0; nt < 3; ++nt)
                acc[m2][nt] = __builtin_amdgcn_mfma_f32_16x16x32_bf16(wf, e[nt], acc[m2][nt], 0, 0, 0);
        }
    }
}

// stage one node's h_E tile (fp32 global) into bf16 swizzled LDS (256 threads)
__device__ inline void stage_hE(const float* __restrict__ Eb, short* A_sw, int tidn) {
#pragma unroll
    for (int i = 0; i < 3; ++i) {
        int e = tidn + i * 256;
        int r = e >> 4, c0 = (e & 15) * 8;
        float4 f0 = *(const float4*)(Eb + r * 128 + c0);
        float4 f1 = *(const float4*)(Eb + r * 128 + c0 + 4);
        uint4 u;
        u.x = cvt_pk_bf16(f0.x, f0.y); u.y = cvt_pk_bf16(f0.z, f0.w);
        u.z = cvt_pk_bf16(f1.x, f1.y); u.w = cvt_pk_bf16(f1.z, f1.w);
        *(uint4*)((char*)A_sw + r * 256 + ((c0 * 2) ^ ((r & 7) << 4))) = u;
    }
}

// gather 48 rows of Yn[E_idx] (bf16, 128 cols) into LDS with stride 136 (256 thr)
__device__ inline void gather_Yn(const short* __restrict__ Yng, const int* __restrict__ Eidx,
                                 int node, int bb, int tidn, short* Ygb) {
    if (tidn < 192) {
        int r = tidn >> 2, q = tidn & 3;
        int idx = Eidx[node * 48 + r];
        const short8* src = (const short8*)(Yng + ((size_t)bb * 2048 + idx) * 128 + q * 32);
        short8* dst = (short8*)(Ygb + r * 136 + q * 32);
        dst[0] = src[0];
        dst[1] = src[1];
        dst[2] = src[2];
        dst[3] = src[3];
    }
}

// layer-1 epilogue (swapped): v = gelu(acc + Ys[feat] + Yn[edge][feat]) -> tile
__device__ inline void epi_l1(f32x4 acc[2][3], const float* Ysh, const short* Ygb,
                              short* A_sw, int w, int lane) {
#pragma unroll
    for (int m2 = 0; m2 < 2; ++m2) {
        int featb = (w * 2 + m2) * 16 + ((lane >> 4) << 2);
        float ys0 = Ysh[featb], ys1 = Ysh[featb + 1];
        float ys2 = Ysh[featb + 2], ys3 = Ysh[featb + 3];
#pragma unroll
        for (int nt = 0; nt < 3; ++nt) {
            int edge = nt * 16 + (lane & 15);
            uint2 yv = *(const uint2*)(Ygb + edge * 136 + featb);
            float v0 = gelu_fast(acc[m2][nt][0] + ys0 + bflo(yv.x));
            float v1 = gelu_fast(acc[m2][nt][1] + ys1 + bfhi(yv.x));
            float v2 = gelu_fast(acc[m2][nt][2] + ys2 + bflo(yv.y));
            float v3 = gelu_fast(acc[m2][nt][3] + ys3 + bfhi(yv.y));
            uint2 pk = {cvt_pk_bf16(v0, v1), cvt_pk_bf16(v2, v3)};
            *(uint2*)((char*)A_sw + edge * 256 + ((featb * 2) ^ ((edge & 7) << 4))) = pk;
        }
    }
}

// layer-2 epilogue (swapped): v = gelu(acc + b[feat]) -> tile
__device__ inline void epi_l2(f32x4 acc[2][3], const float* __restrict__ b,
                              short* A_sw, int w, int lane) {
#pragma unroll
    for (int m2 = 0; m2 < 2; ++m2) {
        int featb = (w * 2 + m2) * 16 + ((lane >> 4) << 2);
        float b0 = b[featb], b1 = b[featb + 1], b2v = b[featb + 2], b3v = b[featb + 3];
#pragma unroll
        for (int nt = 0; nt < 3; ++nt) {
            int edge = nt * 16 + (lane & 15);
            float v0 = gelu_fast(acc[m2][nt][0] + b0);
            float v1 = gelu_fast(acc[m2][nt][1] + b1);
            float v2 = gelu_fast(acc[m2][nt][2] + b2v);
            float v3 = gelu_fast(acc[m2][nt][3] + b3v);
            uint2 pk = {cvt_pk_bf16(v0, v1), cvt_pk_bf16(v2, v3)};
            *(uint2*)((char*)A_sw + edge * 256 + ((featb * 2) ^ ((edge & 7) << 4))) = pk;
        }
    }
}

// ---- node message MLP + masked mean + LN1 (2 nodes per 512-thread block) ----
__global__ __launch_bounds__(512) void node_msg_kernel(
    const float* __restrict__ hV, const float* __restrict__ hE,
    const int* __restrict__ Eidx, const float* __restrict__ maskAtt,
    const short8* __restrict__ W1bp, const short8* __restrict__ W2p,
    const short8* __restrict__ W3p, const float* __restrict__ b2,
    const float* __restrict__ b3, const float* __restrict__ Ysg,
    const short* __restrict__ Yng, const float* __restrict__ g1,
    const float* __restrict__ be1, float* __restrict__ hv1out) {
    const int tid = threadIdx.x;
    const int nd = tid >> 8;          // which of the 2 nodes
    const int tidn = tid & 255;       // thread id within node-group
    const int node = blockIdx.x * 2 + nd;
    const int bb = node >> 11;
    const int lane = tid & 63, w = (tid >> 6) & 3;

    __shared__ __align__(16) short A_sw[2][48 * 128];
    __shared__ __align__(16) short Ygb[2][48 * 136];
    __shared__ float Ysh[2][128];
    __shared__ float mask_s[2][48];
    __shared__ float red[2][8];

    stage_hE(hE + (size_t)node * 6144, A_sw[nd], tidn);
    if (tidn < 128) Ysh[nd][tidn] = Ysg[(size_t)node * 128 + tidn];
    if (tidn >= 192 && tidn < 240) mask_s[nd][tidn - 192] = maskAtt[node * 48 + tidn - 192];
    gather_Yn(Yng, Eidx, node, bb, tidn, Ygb[nd]);
    __syncthreads();

    f32x4 acc[2][3];
    gemm48_swz(A_sw[nd], W1bp, w, lane, acc);
    __syncthreads();
    epi_l1(acc, Ysh[nd], Ygb[nd], A_sw[nd], w, lane);
    __syncthreads();
    gemm48_swz(A_sw[nd], W2p, w, lane, acc);
    __syncthreads();
    epi_l2(acc, b2, A_sw[nd], w, lane);
    __syncthreads();

    // layer 3 (old orientation) + masked column-sum straight from accumulators
    f32x4 acc3[3][2];
    gemm48_a(A_sw[nd], W3p, w, lane, acc3);
    float u[2];
#pragma unroll
    for (int n2 = 0; n2 < 2; ++n2) {
        int col = (w * 2 + n2) * 16 + (lane & 15);
        float b3c = b3[col];
        float s = 0.f;
#pragma unroll
        for (int mt = 0; mt < 3; ++mt)
#pragma unroll
            for (int i = 0; i < 4; ++i) {
                int row = mt * 16 + (lane >> 4) * 4 + i;
                s += (acc3[mt][n2][i] + b3c) * mask_s[nd][row];
            }
        s += __shfl_xor(s, 16, 64);
        s += __shfl_xor(s, 32, 64);   // total over all 48 rows, replicated
        u[n2] = hV[(size_t)node * 128 + col] + s * (1.0f / 30.0f);
    }
    // LN1 over 128 cols (each wave owns 32 cols, values replicated 4x in-wave)
    float ps = wred(u[0] + u[1]) * 0.25f;
    float pq = wred(u[0] * u[0] + u[1] * u[1]) * 0.25f;
    if (lane == 0) { red[nd][w] = ps; red[nd][4 + w] = pq; }
    __syncthreads();
    float S = red[nd][0] + red[nd][1] + red[nd][2] + red[nd][3];
    float Q = red[nd][4] + red[nd][5] + red[nd][6] + red[nd][7];
    float mu = S * (1.0f / 128.0f);
    float var = Q * (1.0f / 128.0f) - mu * mu;
    float rs = rsqrtf(var + 1e-5f);
    if ((lane >> 4) == 0) {
#pragma unroll
        for (int n2 = 0; n2 < 2; ++n2) {
            int col = (w * 2 + n2) * 16 + (lane & 15);
            hv1out[(size_t)node * 128 + col] = (u[n2] - mu) * rs * g1[col] + be1[col];
        }
    }
}

// ---- FFN via MFMA: [16x128]@[128x512] gelu @[512x128] + residual + LN2 ------
__global__ __launch_bounds__(256) void ffn_kernel(
    const float* __restrict__ hv1, const short8* __restrict__ Winp,
    const float* __restrict__ binp, const short8* __restrict__ Woutp,
    const float* __restrict__ bout, const float* __restrict__ g2,
    const float* __restrict__ be2, const float* __restrict__ maskV,
    float* __restrict__ hVout) {
    int n0 = blockIdx.x * 16;
    int tid = threadIdx.x, lane = tid & 63, w = tid >> 6;
    __shared__ float X[16 * 128];
    __shared__ __align__(16) short A_sw[16 * 128];
    __shared__ __align__(16) short H_sw[16 * 512];

    {
        int off = tid * 8;
        int r = off >> 7, c0 = off & 127;
        const float* src = hv1 + (size_t)n0 * 128 + off;
        float4 f0 = *(const float4*)(src);
        float4 f1 = *(const float4*)(src + 4);
        *(float4*)(&X[off]) = f0;
        *(float4*)(&X[off + 4]) = f1;
        uint4 u;
        u.x = cvt_pk_bf16(f0.x, f0.y); u.y = cvt_pk_bf16(f0.z, f0.w);
        u.z = cvt_pk_bf16(f1.x, f1.y); u.w = cvt_pk_bf16(f1.z, f1.w);
        *(uint4*)((char*)A_sw + r * 256 + ((c0 * 2) ^ ((r & 7) << 4))) = u;
    }
    __syncthreads();

    f32x4 acc1[8];
#pragma unroll
    for (int n2 = 0; n2 < 8; ++n2) acc1[n2] = (f32x4){0.f, 0.f, 0.f, 0.f};
#pragma unroll
    for (int kt = 0; kt < 4; ++kt) {
        int row = lane & 15;
        int kb = (kt * 32 + (lane >> 4) * 8) * 2;
        short8 a = *(const short8*)((const char*)A_sw + row * 256 + (kb ^ ((row & 7) << 4)));
#pragma unroll
        for (int n2 = 0; n2 < 8; ++n2) {
            short8 bf = Winp[((w * 8 + n2) * 4 + kt) * 64 + lane];
            acc1[n2] = __builtin_amdgcn_mfma_f32_16x16x32_bf16(a, bf, acc1[n2], 0, 0, 0);
        }
    }
#pragma unroll
    for (int n2 = 0; n2 < 8; ++n2) {
        int col = (w * 8 + n2) * 16 + (lane & 15);
        float bv = binp[col];
#pragma unroll
        for (int i = 0; i < 4; ++i) {
            int row = (lane >> 4) * 4 + i;
            float v = gelu_fast(acc1[n2][i] + bv);
            *(short*)((char*)H_sw + row * 1024 + ((col * 2) ^ ((row & 7) << 4))) = f2bf(v);
        }
    }
    __syncthreads();

    f32x4 acc2[2];
    acc2[0] = (f32x4){0.f, 0.f, 0.f, 0.f};
    acc2[1] = (f32x4){0.f, 0.f, 0.f, 0.f};
#pragma unroll
    for (int kt = 0; kt < 16; ++kt) {
        int row = lane & 15;
        int kb = (kt * 32 + (lane >> 4) * 8) * 2;
        short8 a = *(const short8*)((const char*)H_sw + row * 1024 + (kb ^ ((row & 7) << 4)));
#pragma unroll
        for (int n2 = 0; n2 < 2; ++n2) {
            short8 bf = Woutp[((w * 2 + n2) * 16 + kt) * 64 + lane];
            acc2[n2] = __builtin_amdgcn_mfma_f32_16x16x32_bf16(a, bf, acc2[n2], 0, 0, 0);
        }
    }
#pragma unroll
    for (int n2 = 0; n2 < 2; ++n2) {
        int col = (w * 2 + n2) * 16 + (lane & 15);
        float bo = bout[col];
#pragma unroll
        for (int i = 0; i < 4; ++i) {
            int row = (lane >> 4) * 4 + i;
            X[row * 128 + col] += acc2[n2][i] + bo;
        }
    }
    __syncthreads();

#pragma unroll
    for (int p = 0; p < 4; ++p) {
        int r = p * 4 + w;
        float u0 = X[r * 128 + lane], u1 = X[r * 128 + lane + 64];
        float s = wred(u0 + u1);
        float q = wred(u0 * u0 + u1 * u1);
        float mu = s * (1.0f / 128.0f);
        float var = q * (1.0f / 128.0f) - mu * mu;
        float rs = rsqrtf(var + 1e-5f);
        float mv = maskV[n0 + r];
        hVout[(size_t)(n0 + r) * 128 + lane] = mv * ((u0 - mu) * rs * g2[lane] + be2[lane]);
        hVout[(size_t)(n0 + r) * 128 + lane + 64] = mv * ((u1 - mu) * rs * g2[lane + 64] + be2[lane + 64]);
    }
}

// ---- edge update MLP + residual + LN3 (2 nodes per 512-thread block) --------
__global__ __launch_bounds__(512) void edge_upd_kernel(
    const float* __restrict__ hE, const int* __restrict__ Eidx,
    const short8* __restrict__ W11bp, const short8* __restrict__ W12p,
    const short8* __restrict__ W13p, const float* __restrict__ b12,
    const float* __restrict__ b13, const float* __restrict__ Ysg,
    const short* __restrict__ Yng, const float* __restrict__ g3,
    const float* __restrict__ be3, float* __restrict__ hEout) {
    const int tid = threadIdx.x;
    const int nd = tid >> 8;
    const int tidn = tid & 255;
    const int node = blockIdx.x * 2 + nd;
    const int bb = node >> 11;
    const int lane = tid & 63, w = (tid >> 6) & 3;

    __shared__ __align__(16) short A_sw[2][48 * 128];
    __shared__ __align__(16) short Ygb[2][48 * 136];  // gather, then pre-LN stash
    __shared__ float Ysh[2][128];

    const float* Eb = hE + (size_t)node * 6144;
    stage_hE(Eb, A_sw[nd], tidn);
    if (tidn < 128) Ysh[nd][tidn] = Ysg[(size_t)node * 128 + tidn];
    gather_Yn(Yng, Eidx, node, bb, tidn, Ygb[nd]);
    __syncthreads();

    f32x4 acc[2][3];
    gemm48_swz(A_sw[nd], W11bp, w, lane, acc);
    __syncthreads();
    epi_l1(acc, Ysh[nd], Ygb[nd], A_sw[nd], w, lane);
    __syncthreads();
    gemm48_swz(A_sw[nd], W12p, w, lane, acc);
    __syncthreads();
    epi_l2(acc, b12, A_sw[nd], w, lane);
    __syncthreads();

    // layer 3 (old orientation): pre-LN = msg + b13 + residual(re-read fp32)
    f32x4 acc3[3][2];
    gemm48_a(A_sw[nd], W13p, w, lane, acc3);
#pragma unroll
    for (int mt = 0; mt < 3; ++mt)
#pragma unroll
        for (int n2 = 0; n2 < 2; ++n2) {
            int col = (w * 2 + n2) * 16 + (lane & 15);
            float bv = b13[col];
#pragma unroll
            for (int i = 0; i < 4; ++i) {
                int row = mt * 16 + (lane >> 4) * 4 + i;
                float v = acc3[mt][n2][i] + bv + Eb[row * 128 + col];
                Ygb[nd][row * 136 + col] = f2bf(v);
            }
        }
    __syncthreads();

    // LN per edge row (wave per row within node-group), coalesced output
    float* outb = hEout + (size_t)node * 6144;
    float gl0 = g3[lane], gl1 = g3[lane + 64];
    float bl0 = be3[lane], bl1 = be3[lane + 64];
#pragma unroll
    for (int p = 0; p < 12; ++p) {
        int r = p * 4 + w;
        float u0 = bf2f(Ygb[nd][r * 136 + lane]);
        float u1 = bf2f(Ygb[nd][r * 136 + lane + 64]);
        float s = wred(u0 + u1);
        float q = wred(u0 * u0 + u1 * u1);
        float mu = s * (1.0f / 128.0f);
        float var = q * (1.0f / 128.0f) - mu * mu;
        float rs = rsqrtf(var + 1e-5f);
        outb[r * 128 + lane] = (u0 - mu) * rs * gl0 + bl0;
        outb[r * 128 + lane + 64] = (u1 - mu) * rs * gl1 + bl1;
    }
}

extern "C" void kernel_launch(void* const* d_in, const int* in_sizes, int n_in,
                              void* d_out, int out_size, void* d_ws, size_t ws_size,
                              hipStream_t stream) {
    const float* hV      = (const float*)d_in[0];
    const float* hE      = (const float*)d_in[1];
    const int*   Eidx    = (const int*)d_in[2];
    const float* maskV   = (const float*)d_in[3];
    const float* maskAtt = (const float*)d_in[4];
    const float* W1  = (const float*)d_in[5];
    const float* b1  = (const float*)d_in[6];
    const float* W2  = (const float*)d_in[7];
    const float* b2  = (const float*)d_in[8];
    const float* W3  = (const float*)d_in[9];
    const float* b3  = (const float*)d_in[10];
    const float* W11 = (const float*)d_in[11];
    const float* b11 = (const float*)d_in[12];
    const float* W12 = (const float*)d_in[13];
    const float* b12 = (const float*)d_in[14];
    const float* W13 = (const float*)d_in[15];
    const float* b13 = (const float*)d_in[16];
    const float* Win = (const float*)d_in[17];
    const float* binp= (const float*)d_in[18];
    const float* Wout= (const float*)d_in[19];
    const float* bout= (const float*)d_in[20];
    const float* g1  = (const float*)d_in[21];
    const float* be1 = (const float*)d_in[22];
    const float* g2  = (const float*)d_in[23];
    const float* be2 = (const float*)d_in[24];
    const float* g3  = (const float*)d_in[25];
    const float* be3 = (const float*)d_in[26];

    char* ws = (char*)d_ws;
    short* Wpk  = (short*)ws;
    float* Ys   = (float*)(ws + 1048576);
    short* Yn   = (short*)(ws + 1048576 + 2097152);
    float* hv1  = (float*)(ws + 1048576 + 2097152 + 1048576);

    float* hVout = (float*)d_out;
    float* hEout = hVout + 2 * 2048 * 128;

    const int NNODE = 2 * 2048;

    pack_all_kernel<<<144, 256, 0, stream>>>(W1, W2, W3, W11, W12, W13, Win, Wout, Wpk);

    node_pre_kernel<<<NNODE / 16, 256, 0, stream>>>(hV,
        (const short8*)(Wpk + 98304), (const short8*)(Wpk + 114688), b1, Ys, Yn);

    node_msg_kernel<<<NNODE / 2, 512, 0, stream>>>(hV, hE, Eidx, maskAtt,
        (const short8*)(Wpk), (const short8*)(Wpk + 16384), (const short8*)(Wpk + 32768),
        b2, b3, Ys, Yn, g1, be1, hv1);

    ffn_kernel<<<NNODE / 16, 256, 0, stream>>>(hv1,
        (const short8*)(Wpk + 163840), binp, (const short8*)(Wpk + 229376), bout,
        g2, be2, maskV, hVout);

    node_pre_kernel<<<NNODE / 16, 256, 0, stream>>>(hVout,
        (const short8*)(Wpk + 131072), (const short8*)(Wpk + 147456), b11, Ys, Yn);

    edge_upd_kernel<<<NNODE / 2, 512, 0, stream>>>(hE, Eidx,
        (const short8*)(Wpk + 49152), (const short8*)(Wpk + 65536), (const short8*)(Wpk + 81920),
        b12, b13, Ys, Yn, g3, be3, hEout);
}

// Round 11
// 137.711 us; speedup vs baseline: 1.8522x; 1.1135x over previous
//
#include <hip/hip_runtime.h>
#include <hip/hip_bf16.h>

typedef __attribute__((ext_vector_type(8))) short short8;
typedef __attribute__((ext_vector_type(4))) float f32x4;

__device__ inline short f2bf(float f) {
    unsigned u = __builtin_bit_cast(unsigned, f);
    u += 0x7fffu + ((u >> 16) & 1u);
    return (short)(u >> 16);
}
__device__ inline float bf2f(short s) {
    return __builtin_bit_cast(float, ((unsigned)(unsigned short)s) << 16);
}
__device__ inline float bflo(unsigned u) { return __builtin_bit_cast(float, u << 16); }
__device__ inline float bfhi(unsigned u) { return __builtin_bit_cast(float, u & 0xffff0000u); }
__device__ inline unsigned cvt_pk_bf16(float a, float b) {
    unsigned r;
    asm("v_cvt_pk_bf16_f32 %0, %1, %2" : "=v"(r) : "v"(a), "v"(b));
    return r;
}
// tanh-form gelu: max abs err ~3e-3 vs exact
__device__ inline float gelu_fast(float x) {
    float z = x * (1.0f + 0.044715f * x * x);
    float e = __expf(1.5957691216f * z);
    return x - x * __builtin_amdgcn_rcpf(e + 1.0f);
}
__device__ inline float wred(float s) {
#pragma unroll
    for (int o = 32; o; o >>= 1) s += __shfl_xor(s, o, 64);
    return s;
}

// ---- pack all weights into bf16 MFMA-B fragment order -----------------------
__global__ void pack_all_kernel(const float* __restrict__ W1, const float* __restrict__ W2,
                                const float* __restrict__ W3, const float* __restrict__ W11,
                                const float* __restrict__ W12, const float* __restrict__ W13,
                                const float* __restrict__ Win, const float* __restrict__ Wout,
                                short* __restrict__ out) {
    int b = blockIdx.x;
    if (b < 80) {
        int which = b >> 3;
        const float* Ws[10] = {W1 + 128 * 128, W2, W3, W11 + 128 * 128, W12, W13,
                               W1, W1 + 256 * 128, W11, W11 + 256 * 128};
        const float* W = Ws[which];
        int i = (b & 7) * 256 + threadIdx.x;
        int lane = i & 63, tile = i >> 6;
        int kt = tile & 3, nt = tile >> 2;
        int n = nt * 16 + (lane & 15);
        int k0 = kt * 32 + (lane >> 4) * 8;
        short8 v;
#pragma unroll
        for (int j = 0; j < 8; ++j) v[j] = f2bf(W[(size_t)(k0 + j) * 128 + n]);
        *(short8*)(out + (size_t)which * 16384 + (size_t)i * 8) = v;
    } else if (b < 112) {
        int i = (b - 80) * 256 + threadIdx.x;
        int lane = i & 63, tile = i >> 6;
        int kt = tile & 3, nt = tile >> 2;
        int n = nt * 16 + (lane & 15);
        int k0 = kt * 32 + (lane >> 4) * 8;
        short8 v;
#pragma unroll
        for (int j = 0; j < 8; ++j) v[j] = f2bf(Win[(size_t)(k0 + j) * 512 + n]);
        *(short8*)(out + 163840 + (size_t)i * 8) = v;
    } else {
        int i = (b - 112) * 256 + threadIdx.x;
        int lane = i & 63, tile = i >> 6;
        int kt = tile & 15, nt = tile >> 4;
        int n = nt * 16 + (lane & 15);
        int k0 = kt * 32 + (lane >> 4) * 8;
        short8 v;
#pragma unroll
        for (int j = 0; j < 8; ++j) v[j] = f2bf(Wout[(size_t)(k0 + j) * 128 + n]);
        *(short8*)(out + 229376 + (size_t)i * 8) = v;
    }
}

// ---- node precompute via MFMA: Ys = x@Wself+b (f32), Yn = x@Wnbr (bf16) -----
__global__ __launch_bounds__(256) void node_pre_kernel(
    const float* __restrict__ hV, const short8* __restrict__ Bs,
    const short8* __restrict__ Bn, const float* __restrict__ bias,
    float* __restrict__ Ys, short* __restrict__ Yn) {
    int n0 = blockIdx.x * 16;
    int tid = threadIdx.x, lane = tid & 63, w = tid >> 6;
    __shared__ __align__(16) short A_sw[16 * 128];
    {
        int off = tid * 8;
        int r = off >> 7, c0 = off & 127;
        const float* src = hV + (size_t)n0 * 128 + off;
        float4 f0 = *(const float4*)(src);
        float4 f1 = *(const float4*)(src + 4);
        uint4 u;
        u.x = cvt_pk_bf16(f0.x, f0.y); u.y = cvt_pk_bf16(f0.z, f0.w);
        u.z = cvt_pk_bf16(f1.x, f1.y); u.w = cvt_pk_bf16(f1.z, f1.w);
        *(uint4*)((char*)A_sw + r * 256 + ((c0 * 2) ^ ((r & 7) << 4))) = u;
    }
    __syncthreads();
    const short8* Bp = (w < 2) ? Bs : Bn;
    f32x4 acc[4];
#pragma unroll
    for (int n2 = 0; n2 < 4; ++n2) acc[n2] = (f32x4){0.f, 0.f, 0.f, 0.f};
#pragma unroll
    for (int kt = 0; kt < 4; ++kt) {
        int row = lane & 15;
        int kb = (kt * 32 + (lane >> 4) * 8) * 2;
        short8 a = *(const short8*)((const char*)A_sw + row * 256 + (kb ^ ((row & 7) << 4)));
#pragma unroll
        for (int n2 = 0; n2 < 4; ++n2) {
            int ntl = (w & 1) * 4 + n2;
            short8 bf = Bp[(ntl * 4 + kt) * 64 + lane];
            acc[n2] = __builtin_amdgcn_mfma_f32_16x16x32_bf16(a, bf, acc[n2], 0, 0, 0);
        }
    }
    if (w < 2) {
#pragma unroll
        for (int n2 = 0; n2 < 4; ++n2) {
            int col = ((w & 1) * 4 + n2) * 16 + (lane & 15);
            float bv = bias[col];
#pragma unroll
            for (int i = 0; i < 4; ++i) {
                int row = (lane >> 4) * 4 + i;
                Ys[(size_t)(n0 + row) * 128 + col] = acc[n2][i] + bv;
            }
        }
    } else {
#pragma unroll
        for (int n2 = 0; n2 < 4; ++n2) {
            int col = ((w & 1) * 4 + n2) * 16 + (lane & 15);
#pragma unroll
            for (int i = 0; i < 4; ++i) {
                int row = (lane >> 4) * 4 + i;
                Yn[(size_t)(n0 + row) * 128 + col] = f2bf(acc[n2][i]);
            }
        }
    }
}

// ---- GEMM helpers on a 48x128 bf16 edge tile in swizzled LDS ---------------
// Tile byte(edge,feat) = edge*256 + ((feat*2) ^ ((edge&7)<<4))

// old orientation, 2 n-tiles per wave (4-wave kernels)
__device__ inline void gemm48_a(const short* A_sw, const short8* __restrict__ Wp,
                                int w, int lane, f32x4 acc[3][2]) {
#pragma unroll
    for (int mt = 0; mt < 3; ++mt)
#pragma unroll
        for (int n2 = 0; n2 < 2; ++n2) acc[mt][n2] = (f32x4){0.f, 0.f, 0.f, 0.f};
#pragma unroll
    for (int kt = 0; kt < 4; ++kt) {
        short8 a[3];
        int kb = (kt * 32 + (lane >> 4) * 8) * 2;
#pragma unroll
        for (int mt = 0; mt < 3; ++mt) {
            int row = mt * 16 + (lane & 15);
            a[mt] = *(const short8*)((const char*)A_sw + row * 256 + (kb ^ ((row & 7) << 4)));
        }
#pragma unroll
        for (int n2 = 0; n2 < 2; ++n2) {
            short8 bf = Wp[((w * 2 + n2) * 4 + kt) * 64 + lane];
#pragma unroll
            for (int mt = 0; mt < 3; ++mt)
                acc[mt][n2] = __builtin_amdgcn_mfma_f32_16x16x32_bf16(a[mt], bf, acc[mt][n2], 0, 0, 0);
        }
    }
}

// swapped orientation, 2 feat-tiles per wave (4-wave kernels)
__device__ inline void gemm48_swz(const short* A_sw, const short8* __restrict__ Wp,
                                  int w, int lane, f32x4 acc[2][3]) {
#pragma unroll
    for (int m2 = 0; m2 < 2; ++m2)
#pragma unroll
        for (int nt = 0; nt < 3; ++nt) acc[m2][nt] = (f32x4){0.f, 0.f, 0.f, 0.f};
#pragma unroll
    for (int kt = 0; kt < 4; ++kt) {
        int kb = (kt * 32 + (lane >> 4) * 8) * 2;
        short8 e[3];
#pragma unroll
        for (int nt = 0; nt < 3; ++nt) {
            int row = nt * 16 + (lane & 15);
            e[nt] = *(const short8*)((const char*)A_sw + row * 256 + (kb ^ ((row & 7) << 4)));
        }
#pragma unroll
        for (int m2 = 0; m2 < 2; ++m2) {
            short8 wf = Wp[((w * 2 + m2) * 4 + kt) * 64 + lane];
#pragma unroll
            for (int nt = 0; nt < 3; ++nt)
                acc[m2][nt] = __builtin_amdgcn_mfma_f32_16x16x32_bf16(wf, e[nt], acc[m2][nt], 0, 0, 0);
        }
    }
}

// swapped orientation, 1 feat-tile per wave (8-wave edge kernel)
__device__ inline void gemm48_swz1(const short* A_sw, const short8* __restrict__ Wp,
                                   int ft, int lane, f32x4 acc[3]) {
#pragma unroll
    for (int nt = 0; nt < 3; ++nt) acc[nt] = (f32x4){0.f, 0.f, 0.f, 0.f};
#pragma unroll
    for (int kt = 0; kt < 4; ++kt) {
        int kb = (kt * 32 + (lane >> 4) * 8) * 2;
        short8 e[3];
#pragma unroll
        for (int nt = 0; nt < 3; ++nt) {
            int row = nt * 16 + (lane & 15);
            e[nt] = *(const short8*)((const char*)A_sw + row * 256 + (kb ^ ((row & 7) << 4)));
        }
        short8 wf = Wp[(ft * 4 + kt) * 64 + lane];
#pragma unroll
        for (int nt = 0; nt < 3; ++nt)
            acc[nt] = __builtin_amdgcn_mfma_f32_16x16x32_bf16(wf, e[nt], acc[nt], 0, 0, 0);
    }
}

// old orientation, 1 n-tile per wave (8-wave edge kernel)
__device__ inline void gemm48_a1(const short* A_sw, const short8* __restrict__ Wp,
                                 int ft, int lane, f32x4 acc[3]) {
#pragma unroll
    for (int mt = 0; mt < 3; ++mt) acc[mt] = (f32x4){0.f, 0.f, 0.f, 0.f};
#pragma unroll
    for (int kt = 0; kt < 4; ++kt) {
        short8 a[3];
        int kb = (kt * 32 + (lane >> 4) * 8) * 2;
#pragma unroll
        for (int mt = 0; mt < 3; ++mt) {
            int row = mt * 16 + (lane & 15);
            a[mt] = *(const short8*)((const char*)A_sw + row * 256 + (kb ^ ((row & 7) << 4)));
        }
        short8 bf = Wp[(ft * 4 + kt) * 64 + lane];
#pragma unroll
        for (int mt = 0; mt < 3; ++mt)
            acc[mt] = __builtin_amdgcn_mfma_f32_16x16x32_bf16(a[mt], bf, acc[mt], 0, 0, 0);
    }
}

// stage one node's h_E tile (fp32 global) into bf16 swizzled LDS, 256 threads
__device__ inline void stage_hE(const float* __restrict__ Eb, short* A_sw, int tid) {
#pragma unroll
    for (int i = 0; i < 3; ++i) {
        int e = tid + i * 256;
        int r = e >> 4, c0 = (e & 15) * 8;
        float4 f0 = *(const float4*)(Eb + r * 128 + c0);
        float4 f1 = *(const float4*)(Eb + r * 128 + c0 + 4);
        uint4 u;
        u.x = cvt_pk_bf16(f0.x, f0.y); u.y = cvt_pk_bf16(f0.z, f0.w);
        u.z = cvt_pk_bf16(f1.x, f1.y); u.w = cvt_pk_bf16(f1.z, f1.w);
        *(uint4*)((char*)A_sw + r * 256 + ((c0 * 2) ^ ((r & 7) << 4))) = u;
    }
}

// stage variant for 512-thread blocks (768 8-float units)
__device__ inline void stage_hE512(const float* __restrict__ Eb, short* A_sw, int tid) {
#pragma unroll
    for (int i = 0; i < 2; ++i) {
        int e = tid + i * 512;
        if (i == 1 && e >= 768) break;
        int r = e >> 4, c0 = (e & 15) * 8;
        float4 f0 = *(const float4*)(Eb + r * 128 + c0);
        float4 f1 = *(const float4*)(Eb + r * 128 + c0 + 4);
        uint4 u;
        u.x = cvt_pk_bf16(f0.x, f0.y); u.y = cvt_pk_bf16(f0.z, f0.w);
        u.z = cvt_pk_bf16(f1.x, f1.y); u.w = cvt_pk_bf16(f1.z, f1.w);
        *(uint4*)((char*)A_sw + r * 256 + ((c0 * 2) ^ ((r & 7) << 4))) = u;
    }
}

// gather 48 rows of Yn[E_idx] (bf16, 128 cols) into LDS with stride 136
__device__ inline void gather_Yn(const short* __restrict__ Yng, const int* __restrict__ Eidx,
                                 int node, int bb, int tid, short* Ygb) {
    if (tid < 192) {
        int r = tid >> 2, q = tid & 3;
        int idx = Eidx[node * 48 + r];
        const short8* src = (const short8*)(Yng + ((size_t)bb * 2048 + idx) * 128 + q * 32);
        short8* dst = (short8*)(Ygb + r * 136 + q * 32);
        dst[0] = src[0];
        dst[1] = src[1];
        dst[2] = src[2];
        dst[3] = src[3];
    }
}

// layer-1 epilogue, 2 feat-tiles (4-wave)
__device__ inline void epi_l1(f32x4 acc[2][3], const float* Ysh, const short* Ygb,
                              short* A_sw, int w, int lane) {
#pragma unroll
    for (int m2 = 0; m2 < 2; ++m2) {
        int featb = (w * 2 + m2) * 16 + ((lane >> 4) << 2);
        float ys0 = Ysh[featb], ys1 = Ysh[featb + 1];
        float ys2 = Ysh[featb + 2], ys3 = Ysh[featb + 3];
#pragma unroll
        for (int nt = 0; nt < 3; ++nt) {
            int edge = nt * 16 + (lane & 15);
            uint2 yv = *(const uint2*)(Ygb + edge * 136 + featb);
            float v0 = gelu_fast(acc[m2][nt][0] + ys0 + bflo(yv.x));
            float v1 = gelu_fast(acc[m2][nt][1] + ys1 + bfhi(yv.x));
            float v2 = gelu_fast(acc[m2][nt][2] + ys2 + bflo(yv.y));
            float v3 = gelu_fast(acc[m2][nt][3] + ys3 + bfhi(yv.y));
            uint2 pk = {cvt_pk_bf16(v0, v1), cvt_pk_bf16(v2, v3)};
            *(uint2*)((char*)A_sw + edge * 256 + ((featb * 2) ^ ((edge & 7) << 4))) = pk;
        }
    }
}

// layer-2 epilogue, 2 feat-tiles (4-wave)
__device__ inline void epi_l2(f32x4 acc[2][3], const float* __restrict__ b,
                              short* A_sw, int w, int lane) {
#pragma unroll
    for (int m2 = 0; m2 < 2; ++m2) {
        int featb = (w * 2 + m2) * 16 + ((lane >> 4) << 2);
        float b0 = b[featb], b1 = b[featb + 1], b2v = b[featb + 2], b3v = b[featb + 3];
#pragma unroll
        for (int nt = 0; nt < 3; ++nt) {
            int edge = nt * 16 + (lane & 15);
            float v0 = gelu_fast(acc[m2][nt][0] + b0);
            float v1 = gelu_fast(acc[m2][nt][1] + b1);
            float v2 = gelu_fast(acc[m2][nt][2] + b2v);
            float v3 = gelu_fast(acc[m2][nt][3] + b3v);
            uint2 pk = {cvt_pk_bf16(v0, v1), cvt_pk_bf16(v2, v3)};
            *(uint2*)((char*)A_sw + edge * 256 + ((featb * 2) ^ ((edge & 7) << 4))) = pk;
        }
    }
}

// ---- node message MLP + masked mean + LN1 (R5-proven, 256 threads) ----------
__global__ __launch_bounds__(256) void node_msg_kernel(
    const float* __restrict__ hV, const float* __restrict__ hE,
    const int* __restrict__ Eidx, const float* __restrict__ maskAtt,
    const short8* __restrict__ W1bp, const short8* __restrict__ W2p,
    const short8* __restrict__ W3p, const float* __restrict__ b2,
    const float* __restrict__ b3, const float* __restrict__ Ysg,
    const short* __restrict__ Yng, const float* __restrict__ g1,
    const float* __restrict__ be1, float* __restrict__ hv1out) {
    const int node = blockIdx.x;
    const int bb = node >> 11;
    const int tid = threadIdx.x;
    const int lane = tid & 63, w = tid >> 6;

    __shared__ __align__(16) short A_sw[48 * 128];
    __shared__ __align__(16) short Ygb[48 * 136];
    __shared__ float Ysh[128];
    __shared__ float mask_s[48];
    __shared__ float red[8];

    stage_hE(hE + (size_t)node * 6144, A_sw, tid);
    if (tid < 128) Ysh[tid] = Ysg[(size_t)node * 128 + tid];
    if (tid >= 192 && tid < 240) mask_s[tid - 192] = maskAtt[node * 48 + tid - 192];
    gather_Yn(Yng, Eidx, node, bb, tid, Ygb);
    __syncthreads();

    f32x4 acc[2][3];
    gemm48_swz(A_sw, W1bp, w, lane, acc);
    __syncthreads();
    epi_l1(acc, Ysh, Ygb, A_sw, w, lane);
    __syncthreads();
    gemm48_swz(A_sw, W2p, w, lane, acc);
    __syncthreads();
    epi_l2(acc, b2, A_sw, w, lane);
    __syncthreads();

    f32x4 acc3[3][2];
    gemm48_a(A_sw, W3p, w, lane, acc3);
    float u[2];
#pragma unroll
    for (int n2 = 0; n2 < 2; ++n2) {
        int col = (w * 2 + n2) * 16 + (lane & 15);
        float b3c = b3[col];
        float s = 0.f;
#pragma unroll
        for (int mt = 0; mt < 3; ++mt)
#pragma unroll
            for (int i = 0; i < 4; ++i) {
                int row = mt * 16 + (lane >> 4) * 4 + i;
                s += (acc3[mt][n2][i] + b3c) * mask_s[row];
            }
        s += __shfl_xor(s, 16, 64);
        s += __shfl_xor(s, 32, 64);
        u[n2] = hV[(size_t)node * 128 + col] + s * (1.0f / 30.0f);
    }
    float ps = wred(u[0] + u[1]) * 0.25f;
    float pq = wred(u[0] * u[0] + u[1] * u[1]) * 0.25f;
    if (lane == 0) { red[w] = ps; red[4 + w] = pq; }
    __syncthreads();
    float S = red[0] + red[1] + red[2] + red[3];
    float Q = red[4] + red[5] + red[6] + red[7];
    float mu = S * (1.0f / 128.0f);
    float var = Q * (1.0f / 128.0f) - mu * mu;
    float rs = rsqrtf(var + 1e-5f);
    if ((lane >> 4) == 0) {
#pragma unroll
        for (int n2 = 0; n2 < 2; ++n2) {
            int col = (w * 2 + n2) * 16 + (lane & 15);
            hv1out[(size_t)node * 128 + col] = (u[n2] - mu) * rs * g1[col] + be1[col];
        }
    }
}

// ---- FFN via MFMA: [16x128]@[128x512] gelu @[512x128] + residual + LN2 ------
__global__ __launch_bounds__(256) void ffn_kernel(
    const float* __restrict__ hv1, const short8* __restrict__ Winp,
    const float* __restrict__ binp, const short8* __restrict__ Woutp,
    const float* __restrict__ bout, const float* __restrict__ g2,
    const float* __restrict__ be2, const float* __restrict__ maskV,
    float* __restrict__ hVout) {
    int n0 = blockIdx.x * 16;
    int tid = threadIdx.x, lane = tid & 63, w = tid >> 6;
    __shared__ float X[16 * 128];
    __shared__ __align__(16) short A_sw[16 * 128];
    __shared__ __align__(16) short H_sw[16 * 512];

    {
        int off = tid * 8;
        int r = off >> 7, c0 = off & 127;
        const float* src = hv1 + (size_t)n0 * 128 + off;
        float4 f0 = *(const float4*)(src);
        float4 f1 = *(const float4*)(src + 4);
        *(float4*)(&X[off]) = f0;
        *(float4*)(&X[off + 4]) = f1;
        uint4 u;
        u.x = cvt_pk_bf16(f0.x, f0.y); u.y = cvt_pk_bf16(f0.z, f0.w);
        u.z = cvt_pk_bf16(f1.x, f1.y); u.w = cvt_pk_bf16(f1.z, f1.w);
        *(uint4*)((char*)A_sw + r * 256 + ((c0 * 2) ^ ((r & 7) << 4))) = u;
    }
    __syncthreads();

    f32x4 acc1[8];
#pragma unroll
    for (int n2 = 0; n2 < 8; ++n2) acc1[n2] = (f32x4){0.f, 0.f, 0.f, 0.f};
#pragma unroll
    for (int kt = 0; kt < 4; ++kt) {
        int row = lane & 15;
        int kb = (kt * 32 + (lane >> 4) * 8) * 2;
        short8 a = *(const short8*)((const char*)A_sw + row * 256 + (kb ^ ((row & 7) << 4)));
#pragma unroll
        for (int n2 = 0; n2 < 8; ++n2) {
            short8 bf = Winp[((w * 8 + n2) * 4 + kt) * 64 + lane];
            acc1[n2] = __builtin_amdgcn_mfma_f32_16x16x32_bf16(a, bf, acc1[n2], 0, 0, 0);
        }
    }
#pragma unroll
    for (int n2 = 0; n2 < 8; ++n2) {
        int col = (w * 8 + n2) * 16 + (lane & 15);
        float bv = binp[col];
#pragma unroll
        for (int i = 0; i < 4; ++i) {
            int row = (lane >> 4) * 4 + i;
            float v = gelu_fast(acc1[n2][i] + bv);
            *(short*)((char*)H_sw + row * 1024 + ((col * 2) ^ ((row & 7) << 4))) = f2bf(v);
        }
    }
    __syncthreads();

    f32x4 acc2[2];
    acc2[0] = (f32x4){0.f, 0.f, 0.f, 0.f};
    acc2[1] = (f32x4){0.f, 0.f, 0.f, 0.f};
#pragma unroll
    for (int kt = 0; kt < 16; ++kt) {
        int row = lane & 15;
        int kb = (kt * 32 + (lane >> 4) * 8) * 2;
        short8 a = *(const short8*)((const char*)H_sw + row * 1024 + (kb ^ ((row & 7) << 4)));
#pragma unroll
        for (int n2 = 0; n2 < 2; ++n2) {
            short8 bf = Woutp[((w * 2 + n2) * 16 + kt) * 64 + lane];
            acc2[n2] = __builtin_amdgcn_mfma_f32_16x16x32_bf16(a, bf, acc2[n2], 0, 0, 0);
        }
    }
#pragma unroll
    for (int n2 = 0; n2 < 2; ++n2) {
        int col = (w * 2 + n2) * 16 + (lane & 15);
        float bo = bout[col];
#pragma unroll
        for (int i = 0; i < 4; ++i) {
            int row = (lane >> 4) * 4 + i;
            X[row * 128 + col] += acc2[n2][i] + bo;
        }
    }
    __syncthreads();

#pragma unroll
    for (int p = 0; p < 4; ++p) {
        int r = p * 4 + w;
        float u0 = X[r * 128 + lane], u1 = X[r * 128 + lane + 64];
        float s = wred(u0 + u1);
        float q = wred(u0 * u0 + u1 * u1);
        float mu = s * (1.0f / 128.0f);
        float var = q * (1.0f / 128.0f) - mu * mu;
        float rs = rsqrtf(var + 1e-5f);
        float mv = maskV[n0 + r];
        hVout[(size_t)(n0 + r) * 128 + lane] = mv * ((u0 - mu) * rs * g2[lane] + be2[lane]);
        hVout[(size_t)(n0 + r) * 128 + lane + 64] = mv * ((u1 - mu) * rs * g2[lane + 64] + be2[lane + 64]);
    }
}

// ---- edge update MLP + residual + LN3 (8 waves on ONE node) -----------------
__global__ __launch_bounds__(512) void edge_upd_kernel(
    const float* __restrict__ hE, const int* __restrict__ Eidx,
    const short8* __restrict__ W11bp, const short8* __restrict__ W12p,
    const short8* __restrict__ W13p, const float* __restrict__ b12,
    const float* __restrict__ b13, const float* __restrict__ Ysg,
    const short* __restrict__ Yng, const float* __restrict__ g3,
    const float* __restrict__ be3, float* __restrict__ hEout) {
    const int node = blockIdx.x;
    const int bb = node >> 11;
    const int tid = threadIdx.x;
    const int lane = tid & 63, w = tid >> 6;   // w = feat-tile 0..7

    __shared__ __align__(16) short A_sw[48 * 128];
    __shared__ __align__(16) short Ygb[48 * 136];   // gather, then pre-LN stash
    __shared__ float Ysh[128];

    const float* Eb = hE + (size_t)node * 6144;
    stage_hE512(Eb, A_sw, tid);
    if (tid < 128) Ysh[tid] = Ysg[(size_t)node * 128 + tid];
    gather_Yn(Yng, Eidx, node, bb, tid, Ygb);
    __syncthreads();

    // layer 1 (swapped, 1 feat-tile/wave)
    f32x4 acc[3];
    gemm48_swz1(A_sw, W11bp, w, lane, acc);
    __syncthreads();
    {
        int featb = w * 16 + ((lane >> 4) << 2);
        float ys0 = Ysh[featb], ys1 = Ysh[featb + 1];
        float ys2 = Ysh[featb + 2], ys3 = Ysh[featb + 3];
#pragma unroll
        for (int nt = 0; nt < 3; ++nt) {
            int edge = nt * 16 + (lane & 15);
            uint2 yv = *(const uint2*)(Ygb + edge * 136 + featb);
            float v0 = gelu_fast(acc[nt][0] + ys0 + bflo(yv.x));
            float v1 = gelu_fast(acc[nt][1] + ys1 + bfhi(yv.x));
            float v2 = gelu_fast(acc[nt][2] + ys2 + bflo(yv.y));
            float v3 = gelu_fast(acc[nt][3] + ys3 + bfhi(yv.y));
            uint2 pk = {cvt_pk_bf16(v0, v1), cvt_pk_bf16(v2, v3)};
            *(uint2*)((char*)A_sw + edge * 256 + ((featb * 2) ^ ((edge & 7) << 4))) = pk;
        }
    }
    __syncthreads();
    // layer 2
    gemm48_swz1(A_sw, W12p, w, lane, acc);
    __syncthreads();
    {
        int featb = w * 16 + ((lane >> 4) << 2);
        float b0 = b12[featb], b1 = b12[featb + 1];
        float b2v = b12[featb + 2], b3v = b12[featb + 3];
#pragma unroll
        for (int nt = 0; nt < 3; ++nt) {
            int edge = nt * 16 + (lane & 15);
            float v0 = gelu_fast(acc[nt][0] + b0);
            float v1 = gelu_fast(acc[nt][1] + b1);
            float v2 = gelu_fast(acc[nt][2] + b2v);
            float v3 = gelu_fast(acc[nt][3] + b3v);
            uint2 pk = {cvt_pk_bf16(v0, v1), cvt_pk_bf16(v2, v3)};
            *(uint2*)((char*)A_sw + edge * 256 + ((featb * 2) ^ ((edge & 7) << 4))) = pk;
        }
    }
    __syncthreads();

    // layer 3 (old orientation, 1 n-tile/wave): pre-LN = msg + b13 + residual
    f32x4 acc3[3];
    gemm48_a1(A_sw, W13p, w, lane, acc3);
    {
        int col = w * 16 + (lane & 15);
        float bv = b13[col];
#pragma unroll
        for (int mt = 0; mt < 3; ++mt)
#pragma unroll
            for (int i = 0; i < 4; ++i) {
                int row = mt * 16 + (lane >> 4) * 4 + i;
                float v = acc3[mt][i] + bv + Eb[row * 128 + col];
                Ygb[row * 136 + col] = f2bf(v);
            }
    }
    __syncthreads();

    // LN per edge row (wave per row, 6 rows/wave), coalesced output
    float* outb = hEout + (size_t)node * 6144;
    float gl0 = g3[lane], gl1 = g3[lane + 64];
    float bl0 = be3[lane], bl1 = be3[lane + 64];
#pragma unroll
    for (int p = 0; p < 6; ++p) {
        int r = p * 8 + w;
        float u0 = bf2f(Ygb[r * 136 + lane]);
        float u1 = bf2f(Ygb[r * 136 + lane + 64]);
        float s = wred(u0 + u1);
        float q = wred(u0 * u0 + u1 * u1);
        float mu = s * (1.0f / 128.0f);
        float var = q * (1.0f / 128.0f) - mu * mu;
        float rs = rsqrtf(var + 1e-5f);
        outb[r * 128 + lane] = (u0 - mu) * rs * gl0 + bl0;
        outb[r * 128 + lane + 64] = (u1 - mu) * rs * gl1 + bl1;
    }
}

extern "C" void kernel_launch(void* const* d_in, const int* in_sizes, int n_in,
                              void* d_out, int out_size, void* d_ws, size_t ws_size,
                              hipStream_t stream) {
    const float* hV      = (const float*)d_in[0];
    const float* hE      = (const float*)d_in[1];
    const int*   Eidx    = (const int*)d_in[2];
    const float* maskV   = (const float*)d_in[3];
    const float* maskAtt = (const float*)d_in[4];
    const float* W1  = (const float*)d_in[5];
    const float* b1  = (const float*)d_in[6];
    const float* W2  = (const float*)d_in[7];
    const float* b2  = (const float*)d_in[8];
    const float* W3  = (const float*)d_in[9];
    const float* b3  = (const float*)d_in[10];
    const float* W11 = (const float*)d_in[11];
    const float* b11 = (const float*)d_in[12];
    const float* W12 = (const float*)d_in[13];
    const float* b12 = (const float*)d_in[14];
    const float* W13 = (const float*)d_in[15];
    const float* b13 = (const float*)d_in[16];
    const float* Win = (const float*)d_in[17];
    const float* binp= (const float*)d_in[18];
    const float* Wout= (const float*)d_in[19];
    const float* bout= (const float*)d_in[20];
    const float* g1  = (const float*)d_in[21];
    const float* be1 = (const float*)d_in[22];
    const float* g2  = (const float*)d_in[23];
    const float* be2 = (const float*)d_in[24];
    const float* g3  = (const float*)d_in[25];
    const float* be3 = (const float*)d_in[26];

    char* ws = (char*)d_ws;
    short* Wpk  = (short*)ws;
    float* Ys   = (float*)(ws + 1048576);
    short* Yn   = (short*)(ws + 1048576 + 2097152);
    float* hv1  = (float*)(ws + 1048576 + 2097152 + 1048576);

    float* hVout = (float*)d_out;
    float* hEout = hVout + 2 * 2048 * 128;

    const int NNODE = 2 * 2048;

    pack_all_kernel<<<144, 256, 0, stream>>>(W1, W2, W3, W11, W12, W13, Win, Wout, Wpk);

    node_pre_kernel<<<NNODE / 16, 256, 0, stream>>>(hV,
        (const short8*)(Wpk + 98304), (const short8*)(Wpk + 114688), b1, Ys, Yn);

    node_msg_kernel<<<NNODE, 256, 0, stream>>>(hV, hE, Eidx, maskAtt,
        (const short8*)(Wpk), (const short8*)(Wpk + 16384), (const short8*)(Wpk + 32768),
        b2, b3, Ys, Yn, g1, be1, hv1);

    ffn_kernel<<<NNODE / 16, 256, 0, stream>>>(hv1,
        (const short8*)(Wpk + 163840), binp, (const short8*)(Wpk + 229376), bout,
        g2, be2, maskV, hVout);

    node_pre_kernel<<<NNODE / 16, 256, 0, stream>>>(hVout,
        (const short8*)(Wpk + 131072), (const short8*)(Wpk + 147456), b11, Ys, Yn);

    edge_upd_kernel<<<NNODE, 512, 0, stream>>>(hE, Eidx,
        (const short8*)(Wpk + 49152), (const short8*)(Wpk + 65536), (const short8*)(Wpk + 81920),
        b12, b13, Ys, Yn, g3, be3, hEout);
}